// Round 9
// baseline (11273.370 us; speedup 1.0000x reference)
//
#include <hip/hip_runtime.h>
#include <math.h>

#define H 4096
#define E 64
#define T_TOTAL 32768
#define NT 256            // 4 waves; tx = expert pair, ty = 8-token group
#define OFF_W 2097152
#define OFF_I 2162688

#define GLD16(SRC, DST)                                                       \
  __builtin_amdgcn_global_load_lds(                                           \
      (const __attribute__((address_space(1))) void*)(SRC),                   \
      (__attribute__((address_space(3))) void*)(DST), 16, 0, 0)

// One K4 step: prefetch next step's W fragments from LDS, 64 fmaf
// (8 tokens x 2 experts x K4, ascending-K chain == R1), refill the x ring
// 4 steps ahead, then pin the schedule so loads can't be sunk.
#define STEP(S, RNG, WC0, WC1, WN0, WN1)                                      \
  do {                                                                        \
    if ((S) < 31) {                                                           \
      WN0 = *(const float4*)(wp + woff0 + 4 * (((S) + 1) ^ rsw));             \
      WN1 = *(const float4*)(wp + woff1 + 4 * (((S) + 1) ^ rsw));             \
    }                                                                         \
    _Pragma("unroll")                                                         \
    for (int i = 0; i < 8; ++i) {                                             \
      acc[i][0] = fmaf(RNG[i].x, WC0.x, acc[i][0]);                           \
      acc[i][0] = fmaf(RNG[i].y, WC0.y, acc[i][0]);                           \
      acc[i][0] = fmaf(RNG[i].z, WC0.z, acc[i][0]);                           \
      acc[i][0] = fmaf(RNG[i].w, WC0.w, acc[i][0]);                           \
      acc[i][1] = fmaf(RNG[i].x, WC1.x, acc[i][1]);                           \
      acc[i][1] = fmaf(RNG[i].y, WC1.y, acc[i][1]);                           \
      acc[i][1] = fmaf(RNG[i].z, WC1.z, acc[i][1]);                           \
      acc[i][1] = fmaf(RNG[i].w, WC1.w, acc[i][1]);                           \
    }                                                                         \
    if (c * 32 + (S) + 4 < 1024) {                                            \
      _Pragma("unroll")                                                       \
      for (int i = 0; i < 8; ++i)                                             \
        RNG[i] = *(const float4*)(xr + (size_t)i * H + (c * 32 + (S) + 4) * 4); \
    }                                                                         \
    __builtin_amdgcn_sched_barrier(0);                                        \
  } while (0)

#define STEP4(B)                                                              \
  STEP(4 * (B) + 0, rA, wa0, wa1, wb0, wb1);                                  \
  STEP(4 * (B) + 1, rB, wb0, wb1, wa0, wa1);                                  \
  STEP(4 * (B) + 2, rC, wa0, wa1, wb0, wb1);                                  \
  STEP(4 * (B) + 3, rD, wb0, wb1, wa0, wa1);

__global__ __launch_bounds__(NT, 2)   // VGPR cap 256 -> ring must not spill
void moe_router_kernel(const float* __restrict__ x,
                       const float* __restrict__ W,
                       float* __restrict__ out)
{
    __shared__ float wt[2][64 * 128];   // double-buffered W chunk, 64 KB

    const int tid  = threadIdx.x;
    const int tx   = tid & 31;          // expert pair: 2tx, 2tx+1
    const int ty   = tid >> 5;          // token group: ty*8 .. ty*8+7
    const int tok0 = blockIdx.x * 64;

    const float* xr = x + (size_t)(tok0 + ty * 8) * H;

    const int e0    = 2 * tx;
    const int rsw   = tx & 7;           // read swizzle (matches staged layout)
    const int woff0 = e0 * 128;
    const int woff1 = e0 * 128 + 128;

    // W staging map (rule 21: linear LDS dest + inverse-swizzled global src).
    // Flat unit u = j*256+tid -> LDS floats [u*4, u*4+4) = row u>>5,
    // swizzled col4 (u&31); its logical col4 = (u&31) ^ ((row>>1)&7).
    const float* wsrc[8];
    int ldso[8];
#pragma unroll
    for (int j = 0; j < 8; ++j) {
        const int u   = j * 256 + tid;
        const int row = u >> 5;
        const int c4  = (u & 31) ^ ((row >> 1) & 7);
        wsrc[j] = W + (size_t)row * H + c4 * 4;
        ldso[j] = u * 4;
    }

    // ---- prologue: DMA chunk 0, prime x ring with steps 0..3 ----
#pragma unroll
    for (int j = 0; j < 8; ++j) GLD16(wsrc[j], &wt[0][ldso[j]]);

    float4 rA[8], rB[8], rC[8], rD[8];
#pragma unroll
    for (int i = 0; i < 8; ++i) rA[i] = *(const float4*)(xr + (size_t)i * H);
#pragma unroll
    for (int i = 0; i < 8; ++i) rB[i] = *(const float4*)(xr + (size_t)i * H + 4);
#pragma unroll
    for (int i = 0; i < 8; ++i) rC[i] = *(const float4*)(xr + (size_t)i * H + 8);
#pragma unroll
    for (int i = 0; i < 8; ++i) rD[i] = *(const float4*)(xr + (size_t)i * H + 12);

    float acc[8][2];
#pragma unroll
    for (int i = 0; i < 8; ++i) { acc[i][0] = 0.f; acc[i][1] = 0.f; }

    __syncthreads();                    // chunk 0 resident

    float4 wa0, wa1, wb0, wb1;
    for (int c = 0; c < 32; ++c) {
        const float* wp = &wt[c & 1][0];
        // step-0 W fragments for this chunk
        wa0 = *(const float4*)(wp + woff0 + 4 * rsw);
        wa1 = *(const float4*)(wp + woff1 + 4 * rsw);
        // DMA next chunk into the other buffer (drained by the end barrier)
        if (c < 31) {
            float* wn = &wt[(c & 1) ^ 1][0];
#pragma unroll
            for (int j = 0; j < 8; ++j)
                GLD16(wsrc[j] + (size_t)(c + 1) * 128, &wn[ldso[j]]);
        }
        STEP4(0) STEP4(1) STEP4(2) STEP4(3)
        STEP4(4) STEP4(5) STEP4(6) STEP4(7)
        __syncthreads();
    }

    // ---- logits out + LDS exchange (identical to the verified R1 path) ----
    float* lt = &wt[0][0];              // 64 x 65 tile
#pragma unroll
    for (int i = 0; i < 8; ++i) {
        const int t = ty * 8 + i;
        lt[t * 65 + e0]     = acc[i][0];
        lt[t * 65 + e0 + 1] = acc[i][1];
        float2 o; o.x = acc[i][0]; o.y = acc[i][1];
        *(float2*)(out + (size_t)(tok0 + t) * E + e0) = o;
    }
    __syncthreads();

    if (tid < 64) {
        const float* row = lt + tid * 65;
        float v1 = -INFINITY, v2 = -INFINITY;
        int i1 = 0, i2 = 0;
        for (int e = 0; e < E; ++e) {
            float v = row[e];
            if (v > v1)      { v2 = v1; i2 = i1; v1 = v; i1 = e; }
            else if (v > v2) { v2 = v;  i2 = e; }
        }
        // softmax -> top2 -> renorm == sigmoid of logit gap (Z cancels)
        float ee = expf(v2 - v1);
        float w1 = 1.0f / (1.0f + ee);
        float w2 = ee * w1;

        const size_t tok = (size_t)tok0 + tid;
        out[OFF_W + tok * 2]     = w1;
        out[OFF_W + tok * 2 + 1] = w2;
        out[OFF_I + tok * 2]     = (float)i1;
        out[OFF_I + tok * 2 + 1] = (float)i2;
    }
}

extern "C" void kernel_launch(void* const* d_in, const int* in_sizes, int n_in,
                              void* d_out, int out_size, void* d_ws, size_t ws_size,
                              hipStream_t stream) {
    const float* x = (const float*)d_in[0];
    const float* W = (const float*)d_in[1];
    float* out = (float*)d_out;

    dim3 grid(T_TOTAL / 64);   // 512 blocks -> 2 blocks/CU (LDS 2x64KB), 8 waves/CU
    dim3 block(NT);
    moe_router_kernel<<<grid, block, 0, stream>>>(x, W, out);
}

// Round 12
// 376.235 us; speedup vs baseline: 29.9636x; 29.9636x over previous
//
#include <hip/hip_runtime.h>
#include <math.h>

#define H 4096
#define E 64
#define T_TOTAL 32768
#define TB 64             // tokens per block
#define NT 256            // 4 waves; tg = tid&15 (token quad), eg = tid>>4 (expert quad)
#define KC 64             // K per chunk
#define NCH (H / KC)      // 64 chunks
#define OFF_W 2097152
#define OFF_I 2162688

#define AS1 __attribute__((address_space(1)))
#define AS3 __attribute__((address_space(3)))

// Proven (R9 passed correctness): 16B global->LDS DMA, linear LDS dest.
#define GLD16(SRC, DST)                                                      \
  __builtin_amdgcn_global_load_lds((const AS1 void*)(SRC), (AS3 void*)(DST), \
                                   16, 0, 0)

// Bank swizzle: logical col4 c of row r stored at slot c ^ swz(r).
__device__ __forceinline__ int swz(int row) { return (row ^ (row >> 4)) & 15; }

__global__ __launch_bounds__(NT, 2)
void moe_router_kernel(const float* __restrict__ x,
                       const float* __restrict__ W,
                       float* __restrict__ out)
{
    // Double-buffered tiles, [64 rows][16 slots of 16B], slot-swizzled. 64 KB.
    __shared__ float xt[2][TB * KC];
    __shared__ float wt[2][E * KC];

    const int tid  = threadIdx.x;
    const int tg   = tid & 15;          // token quad 4tg..4tg+3
    const int eg   = tid >> 4;          // expert quad 4eg..4eg+3
    const int tok0 = blockIdx.x * TB;

    // ---- DMA source maps (rule 21: linear dest unit u, inverse-swz source) ----
    // unit u (0..1023): row = u>>4, slot = u&15, logical col4 = slot ^ swz(row)
    const float* xsrc[4];
    const float* wsrc[4];
    int dsto[4];
#pragma unroll
    for (int k = 0; k < 4; ++k) {
        const int u   = tid + k * NT;
        const int row = u >> 4;
        const int c4  = (u & 15) ^ swz(row);
        xsrc[k] = x + (size_t)(tok0 + row) * H + (c4 << 2);
        wsrc[k] = W + (size_t)row * H + (c4 << 2);
        dsto[k] = u * 4;                // float offset of 16B unit in tile
    }

    // ---- LDS read bases (float indices; step s reads base ^ (4*s)) ----
    int xbase[4], wbase[4];
#pragma unroll
    for (int i = 0; i < 4; ++i) {
        const int xr = 4 * tg + i;
        const int wr = 4 * eg + i;
        xbase[i] = xr * KC + (swz(xr) << 2);
        wbase[i] = wr * KC + (swz(wr) << 2);
    }

    float acc[4][4];
#pragma unroll
    for (int i = 0; i < 4; ++i)
#pragma unroll
        for (int j = 0; j < 4; ++j) acc[i][j] = 0.f;

    // ---- prologue: DMA chunk 0 into buffer 0 ----
#pragma unroll
    for (int k = 0; k < 4; ++k) {
        GLD16(xsrc[k], &xt[0][dsto[k]]);
        GLD16(wsrc[k], &wt[0][dsto[k]]);
    }
    __syncthreads();   // compiler emits vmcnt(0) drain before s_barrier

    for (int c = 0; c < NCH; ++c) {
        const int b = c & 1;

        // DMA next chunk into the other buffer (fire-and-forget; retirement
        // is enforced by the vmcnt(0) the compiler emits at the barrier below)
        if (c + 1 < NCH) {
#pragma unroll
            for (int k = 0; k < 4; ++k) {
                GLD16(xsrc[k] + (c + 1) * KC, &xt[b ^ 1][dsto[k]]);
                GLD16(wsrc[k] + (c + 1) * KC, &wt[b ^ 1][dsto[k]]);
            }
        }

        // ---- compute 16 K4 steps from buffer b ----
        const float* xp = &xt[b][0];
        const float* wp = &wt[b][0];
#pragma unroll
        for (int s = 0; s < 16; ++s) {
            float4 xv[4], wv[4];
#pragma unroll
            for (int i = 0; i < 4; ++i)
                xv[i] = *(const float4*)(xp + (xbase[i] ^ (4 * s)));
#pragma unroll
            for (int j = 0; j < 4; ++j)
                wv[j] = *(const float4*)(wp + (wbase[j] ^ (4 * s)));
            // ascending-K, x/y/z/w per (token,expert) — bit-identical chain
            // to the verified R1/R5/R6 kernels (index tie-safety).
#pragma unroll
            for (int i = 0; i < 4; ++i)
#pragma unroll
                for (int j = 0; j < 4; ++j) {
                    acc[i][j] = fmaf(xv[i].x, wv[j].x, acc[i][j]);
                    acc[i][j] = fmaf(xv[i].y, wv[j].y, acc[i][j]);
                    acc[i][j] = fmaf(xv[i].z, wv[j].z, acc[i][j]);
                    acc[i][j] = fmaf(xv[i].w, wv[j].w, acc[i][j]);
                }
        }

        __syncthreads();   // chunk c done everywhere; chunk c+1 DMA retired
    }

    // ---- logits out (coalesced float4 per owned token) ----
#pragma unroll
    for (int i = 0; i < 4; ++i) {
        float4 v; v.x = acc[i][0]; v.y = acc[i][1]; v.z = acc[i][2]; v.w = acc[i][3];
        *(float4*)(out + (size_t)(tok0 + 4 * tg + i) * E + 4 * eg) = v;
    }

    // ---- exchange for top-2 (reuse xt; 64 x 65 tile) ----
    float* lt = &xt[0][0];
#pragma unroll
    for (int i = 0; i < 4; ++i)
#pragma unroll
        for (int j = 0; j < 4; ++j)
            lt[(4 * tg + i) * 65 + 4 * eg + j] = acc[i][j];
    __syncthreads();

    if (tid < TB) {
        const float* row = lt + tid * 65;
        float v1 = -INFINITY, v2 = -INFINITY;
        int i1 = 0, i2 = 0;
        for (int e = 0; e < E; ++e) {
            float v = row[e];
            if (v > v1)      { v2 = v1; i2 = i1; v1 = v; i1 = e; }
            else if (v > v2) { v2 = v;  i2 = e; }
        }
        // softmax -> top2 -> renorm == sigmoid of logit gap (Z cancels)
        float ee = expf(v2 - v1);
        float w1 = 1.0f / (1.0f + ee);
        float w2 = ee * w1;

        const size_t tok = (size_t)tok0 + tid;
        out[OFF_W + tok * 2]     = w1;
        out[OFF_W + tok * 2 + 1] = w2;
        out[OFF_I + tok * 2]     = (float)i1;
        out[OFF_I + tok * 2 + 1] = (float)i2;
    }
}

extern "C" void kernel_launch(void* const* d_in, const int* in_sizes, int n_in,
                              void* d_out, int out_size, void* d_ws, size_t ws_size,
                              hipStream_t stream) {
    const float* x = (const float*)d_in[0];
    const float* W = (const float*)d_in[1];
    float* out = (float*)d_out;

    dim3 grid(T_TOTAL / TB);   // 512 blocks -> 2 blocks/CU, 2 waves/SIMD
    dim3 block(NT);
    moe_router_kernel<<<grid, block, 0, stream>>>(x, W, out);
}